// Round 1
// baseline (996.765 us; speedup 1.0000x reference)
//
#include <hip/hip_runtime.h>
#include <cmath>

#define MN 20000
#define DM 512
#define NE 640000
#define NH 8

// ===================== fp32 GEMM: C[m,n] = sum_k A[m,k]*W[n,k] + bias[n] ====
// A: M x K row-major; W: N x K row-major (i.e. computes A @ W^T + bias)
#define BM 128
#define BN 128
#define BK 16

__global__ __launch_bounds__(256) void gemm_bt_f32(
    const float* __restrict__ A, const float* __restrict__ W,
    const float* __restrict__ bias, float* __restrict__ Cout,
    int M, int N, int K)
{
    __shared__ __align__(16) float As[BK][BM + 4];
    __shared__ __align__(16) float Bs[BK][BN + 4];
    const int tid  = threadIdx.x;
    const int row0 = blockIdx.x * BM;
    const int col0 = blockIdx.y * BN;
    const int tx = tid & 15;        // 16 thread-cols * 8 = 128
    const int ty = tid >> 4;        // 16 thread-rows * 8 = 128
    const int lr = tid >> 2;        // 0..63 (staging row)
    const int lc = (tid & 3) * 4;   // 0,4,8,12 (staging col)

    float acc[8][8] = {};

    for (int k0 = 0; k0 < K; k0 += BK) {
#pragma unroll
        for (int rr = 0; rr < 2; ++rr) {
            const int r  = lr + rr * 64;
            const int gr = row0 + r;
            float4 av = make_float4(0.f, 0.f, 0.f, 0.f);
            if (gr < M) av = *(const float4*)(A + (size_t)gr * K + (k0 + lc));
            As[lc + 0][r] = av.x; As[lc + 1][r] = av.y;
            As[lc + 2][r] = av.z; As[lc + 3][r] = av.w;
            const int n = col0 + r;   // N is a multiple of 128: no guard
            const float4 bv = *(const float4*)(W + (size_t)n * K + (k0 + lc));
            Bs[lc + 0][r] = bv.x; Bs[lc + 1][r] = bv.y;
            Bs[lc + 2][r] = bv.z; Bs[lc + 3][r] = bv.w;
        }
        __syncthreads();
#pragma unroll
        for (int kk = 0; kk < BK; ++kk) {
            float a[8], b[8];
            *(float4*)&a[0] = *(const float4*)&As[kk][ty * 8 + 0];
            *(float4*)&a[4] = *(const float4*)&As[kk][ty * 8 + 4];
            *(float4*)&b[0] = *(const float4*)&Bs[kk][tx * 8 + 0];
            *(float4*)&b[4] = *(const float4*)&Bs[kk][tx * 8 + 4];
#pragma unroll
            for (int i = 0; i < 8; ++i)
#pragma unroll
                for (int j = 0; j < 8; ++j)
                    acc[i][j] = fmaf(a[i], b[j], acc[i][j]);
        }
        __syncthreads();
    }

#pragma unroll
    for (int i = 0; i < 8; ++i) {
        const int r = row0 + ty * 8 + i;
        if (r >= M) continue;
        float* crow = Cout + (size_t)r * N + col0 + tx * 8;
        const float* brow = bias + col0 + tx * 8;
        float4 o0, o1;
        o0.x = acc[i][0] + brow[0]; o0.y = acc[i][1] + brow[1];
        o0.z = acc[i][2] + brow[2]; o0.w = acc[i][3] + brow[3];
        o1.x = acc[i][4] + brow[4]; o1.y = acc[i][5] + brow[5];
        o1.z = acc[i][6] + brow[6]; o1.w = acc[i][7] + brow[7];
        *(float4*)(crow + 0) = o0;
        *(float4*)(crow + 4) = o1;
    }
}

// ===================== CSR build ============================================
__global__ void count_edges_k(const int* __restrict__ tgt, int* __restrict__ counts, int E)
{
    int e = blockIdx.x * blockDim.x + threadIdx.x;
    if (e < E) atomicAdd(&counts[tgt[e]], 1);
}

// single-block exclusive scan of counts[0..M-1] -> indptr[0..M]
__global__ __launch_bounds__(1024) void scan_counts_k(
    const int* __restrict__ counts, int* __restrict__ indptr, int M)
{
    __shared__ int part[1024];
    const int t  = threadIdx.x;
    const int CH = (M + 1023) / 1024;
    const int base = t * CH;
    int sum = 0;
    for (int i = 0; i < CH; ++i) {
        int idx = base + i;
        if (idx < M) sum += counts[idx];
    }
    part[t] = sum;
    __syncthreads();
    for (int off = 1; off < 1024; off <<= 1) {
        int v = (t >= off) ? part[t - off] : 0;
        __syncthreads();
        part[t] += v;
        __syncthreads();
    }
    int excl = part[t] - sum;   // exclusive prefix for this chunk
    for (int i = 0; i < CH; ++i) {
        int idx = base + i;
        if (idx < M) { indptr[idx] = excl; excl += counts[idx]; }
    }
    if (t == 1023) indptr[M] = part[1023];
}

__global__ void scatter_edges_k(const int* __restrict__ src, const int* __restrict__ tgt,
                                const int* __restrict__ indptr, int* __restrict__ cursor,
                                int* __restrict__ slot_src, int E)
{
    int e = blockIdx.x * blockDim.x + threadIdx.x;
    if (e < E) {
        int t   = tgt[e];
        int pos = atomicAdd(&cursor[t], 1);
        slot_src[indptr[t] + pos] = src[e];
    }
}

// ===================== per-node flash attention =============================
// qkv: M x 1536 (cols 0:512 = q, 512:1536 = kv interleaved per head [k64|v64])
// one block (4 waves) per target node; wave w handles heads w and w+4.
__global__ __launch_bounds__(256) void attn_k(
    const float* __restrict__ qkv, const int* __restrict__ indptr,
    const int* __restrict__ slot_src, float* __restrict__ ob)
{
    const int tgt = blockIdx.x;
    const int w = threadIdx.x >> 6;   // wave 0..3
    const int l = threadIdx.x & 63;   // lane = Dh index
    const int beg = indptr[tgt], end = indptr[tgt + 1];
    const float scale = 0.125f;       // 1/sqrt(64)

    const float q_lo = qkv[(size_t)tgt * 1536 + w * 64 + l];
    const float q_hi = qkv[(size_t)tgt * 1536 + (w + 4) * 64 + l];

    float m_lo = -INFINITY, m_hi = -INFINITY;
    float l_lo = 0.f, l_hi = 0.f;
    float acc_lo = 0.f, acc_hi = 0.f;

    for (int it = beg; it < end; ++it) {
        const int src = slot_src[it];
        const float* kvrow = qkv + (size_t)src * 1536 + 512;
        const float k_lo = kvrow[w * 128 + l];
        const float k_hi = kvrow[(w + 4) * 128 + l];
        const float v_lo = kvrow[w * 128 + 64 + l];
        const float v_hi = kvrow[(w + 4) * 128 + 64 + l];

        float p_lo = q_lo * k_lo;
        float p_hi = q_hi * k_hi;
#pragma unroll
        for (int off = 32; off; off >>= 1) {
            p_lo += __shfl_xor(p_lo, off);
            p_hi += __shfl_xor(p_hi, off);
        }
        const float a_lo = p_lo * scale;
        const float a_hi = p_hi * scale;

        float mn = fmaxf(m_lo, a_lo);
        float f  = __expf(m_lo - mn);
        float we = __expf(a_lo - mn);
        l_lo   = l_lo * f + we;
        acc_lo = acc_lo * f + we * v_lo;
        m_lo   = mn;

        mn = fmaxf(m_hi, a_hi);
        f  = __expf(m_hi - mn);
        we = __expf(a_hi - mn);
        l_hi   = l_hi * f + we;
        acc_hi = acc_hi * f + we * v_hi;
        m_hi   = mn;
    }

    ob[(size_t)tgt * 512 + w * 64 + l]       = (l_lo > 0.f) ? acc_lo / l_lo : 0.f;
    ob[(size_t)tgt * 512 + (w + 4) * 64 + l] = (l_hi > 0.f) ? acc_hi / l_hi : 0.f;
}

// ===================== launch ===============================================
extern "C" void kernel_launch(void* const* d_in, const int* in_sizes, int n_in,
                              void* d_out, int out_size, void* d_ws, size_t ws_size,
                              hipStream_t stream)
{
    const float* s   = (const float*)d_in[0];
    const int*   eix = (const int*)d_in[1];   // [2, E]: row0 = src, row1 = tgt
    const float* Wq  = (const float*)d_in[2];
    const float* bq  = (const float*)d_in[3];
    const float* Wkv = (const float*)d_in[4];
    const float* bkv = (const float*)d_in[5];
    const float* Wo  = (const float*)d_in[6];
    const float* bo  = (const float*)d_in[7];
    float* out = (float*)d_out;

    // workspace layout (16B-aligned chunks)
    char* ws = (char*)d_ws;
    float* qkv = (float*)ws;      ws += (size_t)MN * 1536 * 4;   // 122.9 MB
    float* ob  = (float*)ws;      ws += (size_t)MN * 512 * 4;    //  41.0 MB
    float* Wc  = (float*)ws;      ws += (size_t)1536 * 512 * 4;  //   3.1 MB
    float* bc  = (float*)ws;      ws += 1536 * 4;
    int* counts  = (int*)ws;      ws += MN * 4;
    int* cursor  = (int*)ws;      ws += MN * 4;
    int* slot_src = (int*)ws;     ws += NE * 4;
    int* indptr  = (int*)ws;      ws += (MN + 4) * 4;

    // assemble combined weight [Wq; Wkv] (1536 x 512) and bias
    hipMemcpyAsync(Wc, Wq, (size_t)512 * 512 * 4, hipMemcpyDeviceToDevice, stream);
    hipMemcpyAsync(Wc + (size_t)512 * 512, Wkv, (size_t)1024 * 512 * 4, hipMemcpyDeviceToDevice, stream);
    hipMemcpyAsync(bc, bq, 512 * 4, hipMemcpyDeviceToDevice, stream);
    hipMemcpyAsync(bc + 512, bkv, 1024 * 4, hipMemcpyDeviceToDevice, stream);

    hipMemsetAsync(counts, 0, MN * 4, stream);
    hipMemsetAsync(cursor, 0, MN * 4, stream);

    // QKV projection: qkv = s @ [Wq;Wkv]^T + [bq;bkv]
    dim3 g1((MN + BM - 1) / BM, 1536 / BN);
    gemm_bt_f32<<<g1, 256, 0, stream>>>(s, Wc, bc, qkv, MN, 1536, DM);

    // CSR by target
    count_edges_k<<<NE / 256, 256, 0, stream>>>(eix + NE, counts, NE);
    scan_counts_k<<<1, 1024, 0, stream>>>(counts, indptr, MN);
    scatter_edges_k<<<NE / 256, 256, 0, stream>>>(eix, eix + NE, indptr, cursor, slot_src, NE);

    // per-node online-softmax attention
    attn_k<<<MN, 256, 0, stream>>>(qkv, indptr, slot_src, ob);

    // output projection: out = ob @ Wo^T + bo
    dim3 g2((MN + BM - 1) / BM, 512 / BN);
    gemm_bt_f32<<<g2, 256, 0, stream>>>(ob, Wo, bo, out, MN, 512, DM);
}

// Round 2
// 572.176 us; speedup vs baseline: 1.7421x; 1.7421x over previous
//
#include <hip/hip_runtime.h>
#include <cmath>

#define MN 20000
#define DM 512
#define NE 640000

typedef short bf16x8 __attribute__((ext_vector_type(8)));
typedef float f32x4 __attribute__((ext_vector_type(4)));

// RNE fp32 -> bf16 (no NaN handling needed; inputs are finite)
__device__ __forceinline__ ushort f2b(float x) {
    unsigned u = __builtin_bit_cast(unsigned, x);
    u += 0x7FFF + ((u >> 16) & 1);
    return (ushort)(u >> 16);
}
__device__ __forceinline__ float b2f(ushort b) {
    return __builtin_bit_cast(float, (unsigned)b << 16);
}

// ===================== conversion kernels ===================================
__global__ void conv_bf16_k(const float* __restrict__ in, ushort* __restrict__ out, int n4) {
    int i = blockIdx.x * blockDim.x + threadIdx.x;
    if (i >= n4) return;
    float4 v = ((const float4*)in)[i];
    ushort4 o = { f2b(v.x), f2b(v.y), f2b(v.z), f2b(v.w) };
    ((ushort4*)out)[i] = o;
}

// combined [Wq; Wkv] -> bf16, 1536 x 512
__global__ void conv_wc_k(const float* __restrict__ Wq, const float* __restrict__ Wkv,
                          ushort* __restrict__ out) {
    int i = blockIdx.x * blockDim.x + threadIdx.x;
    if (i >= 1536 * 512 / 4) return;
    int e = i * 4;
    int row = e >> 9, col = e & 511;
    const float* src = (row < 512) ? (Wq + ((size_t)row << 9) + col)
                                   : (Wkv + ((size_t)(row - 512) << 9) + col);
    float4 v = *(const float4*)src;
    ushort4 o = { f2b(v.x), f2b(v.y), f2b(v.z), f2b(v.w) };
    ((ushort4*)out)[i] = o;
}

// fp32 -> (bf16 hi, bf16 lo) split
__global__ void conv_split_k(const float* __restrict__ in, ushort* __restrict__ oh,
                             ushort* __restrict__ ol, int n4) {
    int i = blockIdx.x * blockDim.x + threadIdx.x;
    if (i >= n4) return;
    float4 v = ((const float4*)in)[i];
    ushort4 h, l;
    h.x = f2b(v.x); l.x = f2b(v.x - b2f(h.x));
    h.y = f2b(v.y); l.y = f2b(v.y - b2f(h.y));
    h.z = f2b(v.z); l.z = f2b(v.z - b2f(h.z));
    h.w = f2b(v.w); l.w = f2b(v.w - b2f(h.w));
    ((ushort4*)oh)[i] = h;
    ((ushort4*)ol)[i] = l;
}

// ===================== MFMA GEMM: C = A @ B^T + bias ========================
// A: M x K bf16 row-major (hi[,lo]); B: N x K bf16 row-major (hi[,lo]).
// 128x128 tile, BK=32, 256 threads (4 waves, 2x2 of 64x64 each).
// LDS tiles swizzled: 16B chunk c at row r lives at chunk (c ^ ((r>>1)&3)).
// Staging pre-swizzles the GLOBAL source (global_load_lds writes linearly).
template<int SPLIT, bool OUTBF>
__global__ __launch_bounds__(256) void gemm_mfma(
    const ushort* __restrict__ Ah, const ushort* __restrict__ Al,
    const ushort* __restrict__ Bh, const ushort* __restrict__ Bl,
    const float* __restrict__ bias0, const float* __restrict__ bias1, int bsplit,
    void* __restrict__ Cout, int M, int N, int K)
{
    __shared__ ushort lds[4 * 4096];   // tiles: 0=A_hi 1=B_hi 2=A_lo 3=B_lo (8KB each)
    const int tid = threadIdx.x;
    const int row0 = blockIdx.x * 128, col0 = blockIdx.y * 128;
    const int wid = tid >> 6, l = tid & 63;
    const int wm = (wid >> 1) * 64, wn = (wid & 1) * 64;
    const int fr = l & 15, g = l >> 4;           // frag row select, k-half
    const int fcb = g << 4;                      // frag byte col (pre-swizzle)

    f32x4 acc[4][4] = {};

    for (int k0 = 0; k0 < K; k0 += 32) {
        __syncthreads();
#pragma unroll
        for (int c = 0; c < 2; ++c) {
            const int lb  = c * 4096 + tid * 16;           // linear byte in tile
            const int r   = lb >> 6;                        // tile row
            const int cbs = (lb & 63) ^ ((r & 6) << 3);     // swizzled source chunk
            const int ar  = min(row0 + r, M - 1);
            const int br  = col0 + r;                       // N multiple of 128
            const size_t aoff = (size_t)ar * K + k0 + (cbs >> 1);
            const size_t boff = (size_t)br * K + k0 + (cbs >> 1);
            __builtin_amdgcn_global_load_lds(
                (const __attribute__((address_space(1))) void*)(Ah + aoff),
                (__attribute__((address_space(3))) void*)&lds[0 * 4096 + (lb >> 1)], 16, 0, 0);
            __builtin_amdgcn_global_load_lds(
                (const __attribute__((address_space(1))) void*)(Bh + boff),
                (__attribute__((address_space(3))) void*)&lds[1 * 4096 + (lb >> 1)], 16, 0, 0);
            if (SPLIT == 3) {
                __builtin_amdgcn_global_load_lds(
                    (const __attribute__((address_space(1))) void*)(Al + aoff),
                    (__attribute__((address_space(3))) void*)&lds[2 * 4096 + (lb >> 1)], 16, 0, 0);
                __builtin_amdgcn_global_load_lds(
                    (const __attribute__((address_space(1))) void*)(Bl + boff),
                    (__attribute__((address_space(3))) void*)&lds[3 * 4096 + (lb >> 1)], 16, 0, 0);
            }
        }
        __syncthreads();   // drains vmcnt before barrier -> tiles ready

        bf16x8 ah[4], bh[4], al[4], bl[4];
#pragma unroll
        for (int m = 0; m < 4; ++m) {
            const int r  = wm + m * 16 + fr;
            const int cb = fcb ^ ((r & 6) << 3);
            ah[m] = *(const bf16x8*)&lds[0 * 4096 + r * 32 + (cb >> 1)];
            if (SPLIT == 3) al[m] = *(const bf16x8*)&lds[2 * 4096 + r * 32 + (cb >> 1)];
        }
#pragma unroll
        for (int n = 0; n < 4; ++n) {
            const int r  = wn + n * 16 + fr;
            const int cb = fcb ^ ((r & 6) << 3);
            bh[n] = *(const bf16x8*)&lds[1 * 4096 + r * 32 + (cb >> 1)];
            if (SPLIT == 3) bl[n] = *(const bf16x8*)&lds[3 * 4096 + r * 32 + (cb >> 1)];
        }
#pragma unroll
        for (int m = 0; m < 4; ++m)
#pragma unroll
            for (int n = 0; n < 4; ++n) {
                acc[m][n] = __builtin_amdgcn_mfma_f32_16x16x32_bf16(ah[m], bh[n], acc[m][n], 0, 0, 0);
                if (SPLIT == 3) {
                    acc[m][n] = __builtin_amdgcn_mfma_f32_16x16x32_bf16(ah[m], bl[n], acc[m][n], 0, 0, 0);
                    acc[m][n] = __builtin_amdgcn_mfma_f32_16x16x32_bf16(al[m], bh[n], acc[m][n], 0, 0, 0);
                }
            }
    }

    // epilogue: C/D layout col=lane&15, row=(lane>>4)*4+reg  [m89/m91]
#pragma unroll
    for (int n = 0; n < 4; ++n) {
        const int cg = col0 + wn + n * 16 + fr;
        const float bv = (cg < bsplit) ? bias0[cg] : bias1[cg - bsplit];
#pragma unroll
        for (int m = 0; m < 4; ++m) {
#pragma unroll
            for (int j = 0; j < 4; ++j) {
                const int rg = row0 + wm + m * 16 + g * 4 + j;
                if (rg < M) {
                    const float v = acc[m][n][j] + bv;
                    if (OUTBF) ((ushort*)Cout)[(size_t)rg * N + cg] = f2b(v);
                    else       ((float*)Cout)[(size_t)rg * N + cg] = v;
                }
            }
        }
    }
}

// ===================== CSR build ============================================
__global__ void count_edges_k(const int* __restrict__ tgt, int* __restrict__ counts, int E)
{
    int e = blockIdx.x * blockDim.x + threadIdx.x;
    if (e < E) atomicAdd(&counts[tgt[e]], 1);
}

__global__ __launch_bounds__(1024) void scan_counts_k(
    const int* __restrict__ counts, int* __restrict__ indptr, int M)
{
    __shared__ int part[1024];
    const int t  = threadIdx.x;
    const int CH = (M + 1023) / 1024;
    const int base = t * CH;
    int sum = 0;
    for (int i = 0; i < CH; ++i) {
        int idx = base + i;
        if (idx < M) sum += counts[idx];
    }
    part[t] = sum;
    __syncthreads();
    for (int off = 1; off < 1024; off <<= 1) {
        int v = (t >= off) ? part[t - off] : 0;
        __syncthreads();
        part[t] += v;
        __syncthreads();
    }
    int excl = part[t] - sum;
    for (int i = 0; i < CH; ++i) {
        int idx = base + i;
        if (idx < M) { indptr[idx] = excl; excl += counts[idx]; }
    }
    if (t == 1023) indptr[M] = part[1023];
}

__global__ void scatter_edges_k(const int* __restrict__ src, const int* __restrict__ tgt,
                                const int* __restrict__ indptr, int* __restrict__ cursor,
                                int* __restrict__ slot_src, int E)
{
    int e = blockIdx.x * blockDim.x + threadIdx.x;
    if (e < E) {
        int t   = tgt[e];
        int pos = atomicAdd(&cursor[t], 1);
        slot_src[indptr[t] + pos] = src[e];
    }
}

// ===================== per-node flash attention (bf16 in, split-bf16 out) ===
// qkv: M x 1536 bf16 (cols 0:512 q; 512:1536 kv per head [k64|v64])
__global__ __launch_bounds__(256) void attn_k(
    const ushort* __restrict__ qkv, const int* __restrict__ indptr,
    const int* __restrict__ slot_src, ushort* __restrict__ obh, ushort* __restrict__ obl)
{
    const int tgt = blockIdx.x;
    const int w = threadIdx.x >> 6;   // wave 0..3 -> heads w, w+4
    const int l = threadIdx.x & 63;   // lane = Dh index
    const int beg = indptr[tgt], end = indptr[tgt + 1];
    const float scale = 0.125f;

    const float q_lo = b2f(qkv[(size_t)tgt * 1536 + w * 64 + l]);
    const float q_hi = b2f(qkv[(size_t)tgt * 1536 + (w + 4) * 64 + l]);

    float m_lo = -INFINITY, m_hi = -INFINITY;
    float s_lo = 0.f, s_hi = 0.f;
    float a_lo = 0.f, a_hi = 0.f;

    for (int it = beg; it < end; ++it) {
        const int src = slot_src[it];
        const ushort* kv = qkv + (size_t)src * 1536 + 512;
        const float k0 = b2f(kv[w * 128 + l]);
        const float k1 = b2f(kv[(w + 4) * 128 + l]);
        const float v0 = b2f(kv[w * 128 + 64 + l]);
        const float v1 = b2f(kv[(w + 4) * 128 + 64 + l]);

        float p0 = q_lo * k0;
        float p1 = q_hi * k1;
#pragma unroll
        for (int off = 32; off; off >>= 1) {
            p0 += __shfl_xor(p0, off);
            p1 += __shfl_xor(p1, off);
        }
        const float sc0 = p0 * scale;
        const float sc1 = p1 * scale;

        float mn = fmaxf(m_lo, sc0);
        float f  = __expf(m_lo - mn);
        float we = __expf(sc0 - mn);
        s_lo = s_lo * f + we;
        a_lo = a_lo * f + we * v0;
        m_lo = mn;

        mn = fmaxf(m_hi, sc1);
        f  = __expf(m_hi - mn);
        we = __expf(sc1 - mn);
        s_hi = s_hi * f + we;
        a_hi = a_hi * f + we * v1;
        m_hi = mn;
    }

    const float o0 = (s_lo > 0.f) ? a_lo / s_lo : 0.f;
    const float o1 = (s_hi > 0.f) ? a_hi / s_hi : 0.f;
    const size_t i0 = (size_t)tgt * 512 + w * 64 + l;
    const size_t i1 = (size_t)tgt * 512 + (w + 4) * 64 + l;
    ushort h0 = f2b(o0), h1 = f2b(o1);
    obh[i0] = h0; obl[i0] = f2b(o0 - b2f(h0));
    obh[i1] = h1; obl[i1] = f2b(o1 - b2f(h1));
}

// ===================== launch ===============================================
extern "C" void kernel_launch(void* const* d_in, const int* in_sizes, int n_in,
                              void* d_out, int out_size, void* d_ws, size_t ws_size,
                              hipStream_t stream)
{
    const float* s   = (const float*)d_in[0];
    const int*   eix = (const int*)d_in[1];   // [2, E]: row0 = src, row1 = tgt
    const float* Wq  = (const float*)d_in[2];
    const float* bq  = (const float*)d_in[3];
    const float* Wkv = (const float*)d_in[4];
    const float* bkv = (const float*)d_in[5];
    const float* Wo  = (const float*)d_in[6];
    const float* bo  = (const float*)d_in[7];
    float* out = (float*)d_out;

    // workspace layout (256B aligned)
    char* ws = (char*)d_ws;
    auto take = [&](size_t bytes) { char* p = ws; ws += (bytes + 255) & ~(size_t)255; return p; };
    ushort* qkv_b = (ushort*)take((size_t)MN * 1536 * 2);   // 61.4 MB
    ushort* s_b   = (ushort*)take((size_t)MN * 512 * 2);    // 20.5 MB
    ushort* obh   = (ushort*)take((size_t)MN * 512 * 2);    // 20.5 MB
    ushort* obl   = (ushort*)take((size_t)MN * 512 * 2);    // 20.5 MB
    ushort* Wc_b  = (ushort*)take((size_t)1536 * 512 * 2);  //  1.6 MB
    ushort* Wo_h  = (ushort*)take((size_t)512 * 512 * 2);
    ushort* Wo_l  = (ushort*)take((size_t)512 * 512 * 2);
    int* counts   = (int*)take(MN * 4);
    int* cursor   = (int*)take(MN * 4);
    int* slot_src = (int*)take((size_t)NE * 4);
    int* indptr   = (int*)take((MN + 4) * 4);

    hipMemsetAsync(counts, 0, MN * 4, stream);
    hipMemsetAsync(cursor, 0, MN * 4, stream);

    // conversions
    conv_bf16_k<<<(MN * 512 / 4 + 255) / 256, 256, 0, stream>>>(s, s_b, MN * 512 / 4);
    conv_wc_k<<<(1536 * 512 / 4 + 255) / 256, 256, 0, stream>>>(Wq, Wkv, Wc_b);
    conv_split_k<<<(512 * 512 / 4 + 255) / 256, 256, 0, stream>>>(Wo, Wo_h, Wo_l, 512 * 512 / 4);

    // CSR by target
    count_edges_k<<<NE / 256, 256, 0, stream>>>(eix + NE, counts, NE);
    scan_counts_k<<<1, 1024, 0, stream>>>(counts, indptr, MN);
    scatter_edges_k<<<NE / 256, 256, 0, stream>>>(eix, eix + NE, indptr, cursor, slot_src, NE);

    // QKV projection (pure bf16 MFMA): qkv_b = s_b @ Wc_b^T + [bq;bkv], bf16 out
    dim3 g1((MN + 127) / 128, 1536 / 128);
    gemm_mfma<1, true><<<g1, 256, 0, stream>>>(s_b, s_b, Wc_b, Wc_b, bq, bkv, 512,
                                               qkv_b, MN, 1536, DM);

    // per-node online-softmax attention -> split-bf16 ob
    attn_k<<<MN, 256, 0, stream>>>(qkv_b, indptr, slot_src, obh, obl);

    // output projection (split-bf16, 3 MFMA): out = ob @ Wo^T + bo, fp32 out
    dim3 g2((MN + 127) / 128, 512 / 128);
    gemm_mfma<3, false><<<g2, 256, 0, stream>>>(obh, obl, Wo_h, Wo_l, bo, bo, 1 << 30,
                                                out, MN, 512, DM);
}

// Round 3
// 445.417 us; speedup vs baseline: 2.2378x; 1.2846x over previous
//
#include <hip/hip_runtime.h>
#include <cmath>

#define MN 20000
#define DM 512
#define NE 640000
#define CAP 128   // LDS logit slots per node (max in-degree seen ~70; fallback below)

typedef short bf16x8 __attribute__((ext_vector_type(8)));
typedef float f32x4 __attribute__((ext_vector_type(4)));

// RNE fp32 -> bf16 (inputs finite)
__device__ __forceinline__ ushort f2b(float x) {
    unsigned u = __builtin_bit_cast(unsigned, x);
    u += 0x7FFF + ((u >> 16) & 1);
    return (ushort)(u >> 16);
}
__device__ __forceinline__ float b2f(ushort b) {
    return __builtin_bit_cast(float, (unsigned)b << 16);
}

// ===================== conversion kernels ===================================
__global__ void conv_bf16_k(const float* __restrict__ in, ushort* __restrict__ out, int n4) {
    int i = blockIdx.x * blockDim.x + threadIdx.x;
    if (i >= n4) return;
    float4 v = ((const float4*)in)[i];
    ushort4 o = { f2b(v.x), f2b(v.y), f2b(v.z), f2b(v.w) };
    ((ushort4*)out)[i] = o;
}

// combined weight rows reordered so qkv output cols = [q(512) | k 8x64 | v 8x64]
__device__ __forceinline__ const float* wc_src_row(int r, const float* Wq, const float* Wkv) {
    if (r < 512) return Wq + ((size_t)r << 9);
    if (r < 1024) { int h = (r - 512) >> 6, j = (r - 512) & 63;  return Wkv + ((size_t)(h * 128 + j) << 9); }
    { int h = (r - 1024) >> 6, j = (r - 1024) & 63; return Wkv + ((size_t)(h * 128 + 64 + j) << 9); }
}

__global__ void conv_wc_k(const float* __restrict__ Wq, const float* __restrict__ Wkv,
                          ushort* __restrict__ out) {
    int i = blockIdx.x * blockDim.x + threadIdx.x;
    if (i >= 1536 * 512 / 4) return;
    int e = i * 4;
    int row = e >> 9, col = e & 511;
    float4 v = *(const float4*)(wc_src_row(row, Wq, Wkv) + col);
    ushort4 o = { f2b(v.x), f2b(v.y), f2b(v.z), f2b(v.w) };
    ((ushort4*)out)[i] = o;
}

__global__ void bias_perm_k(const float* __restrict__ bq, const float* __restrict__ bkv,
                            float* __restrict__ bc) {
    int r = blockIdx.x * blockDim.x + threadIdx.x;
    if (r >= 1536) return;
    float v;
    if (r < 512) v = bq[r];
    else if (r < 1024) { int h = (r - 512) >> 6, j = (r - 512) & 63;  v = bkv[h * 128 + j]; }
    else               { int h = (r - 1024) >> 6, j = (r - 1024) & 63; v = bkv[h * 128 + 64 + j]; }
    bc[r] = v;
}

// fp32 -> (bf16 hi, bf16 lo) split
__global__ void conv_split_k(const float* __restrict__ in, ushort* __restrict__ oh,
                             ushort* __restrict__ ol, int n4) {
    int i = blockIdx.x * blockDim.x + threadIdx.x;
    if (i >= n4) return;
    float4 v = ((const float4*)in)[i];
    ushort4 h, l;
    h.x = f2b(v.x); l.x = f2b(v.x - b2f(h.x));
    h.y = f2b(v.y); l.y = f2b(v.y - b2f(h.y));
    h.z = f2b(v.z); l.z = f2b(v.z - b2f(h.z));
    h.w = f2b(v.w); l.w = f2b(v.w - b2f(h.w));
    ((ushort4*)oh)[i] = h;
    ((ushort4*)ol)[i] = l;
}

// ===================== MFMA GEMM: C = A @ B^T + bias ========================
// 128x128 tile, BK=32, 256 threads (4 waves, 2x2 of 64x64). LDS XOR-swizzled
// via pre-swizzled global source (global_load_lds writes linearly).
template<int SPLIT, bool OUTBF>
__global__ __launch_bounds__(256) void gemm_mfma(
    const ushort* __restrict__ Ah, const ushort* __restrict__ Al,
    const ushort* __restrict__ Bh, const ushort* __restrict__ Bl,
    const float* __restrict__ bias, void* __restrict__ Cout, int M, int N, int K)
{
    __shared__ ushort lds[4 * 4096];   // 0=A_hi 1=B_hi 2=A_lo 3=B_lo (8KB each)
    const int tid = threadIdx.x;
    const int row0 = blockIdx.x * 128, col0 = blockIdx.y * 128;
    const int wid = tid >> 6, l = tid & 63;
    const int wm = (wid >> 1) * 64, wn = (wid & 1) * 64;
    const int fr = l & 15, g = l >> 4;
    const int fcb = g << 4;

    f32x4 acc[4][4] = {};

    for (int k0 = 0; k0 < K; k0 += 32) {
        __syncthreads();
#pragma unroll
        for (int c = 0; c < 2; ++c) {
            const int lb  = c * 4096 + tid * 16;
            const int r   = lb >> 6;
            const int cbs = (lb & 63) ^ ((r & 6) << 3);
            const int ar  = min(row0 + r, M - 1);
            const int br  = col0 + r;
            const size_t aoff = (size_t)ar * K + k0 + (cbs >> 1);
            const size_t boff = (size_t)br * K + k0 + (cbs >> 1);
            __builtin_amdgcn_global_load_lds(
                (const __attribute__((address_space(1))) void*)(Ah + aoff),
                (__attribute__((address_space(3))) void*)&lds[0 * 4096 + (lb >> 1)], 16, 0, 0);
            __builtin_amdgcn_global_load_lds(
                (const __attribute__((address_space(1))) void*)(Bh + boff),
                (__attribute__((address_space(3))) void*)&lds[1 * 4096 + (lb >> 1)], 16, 0, 0);
            if (SPLIT == 3) {
                __builtin_amdgcn_global_load_lds(
                    (const __attribute__((address_space(1))) void*)(Al + aoff),
                    (__attribute__((address_space(3))) void*)&lds[2 * 4096 + (lb >> 1)], 16, 0, 0);
                __builtin_amdgcn_global_load_lds(
                    (const __attribute__((address_space(1))) void*)(Bl + boff),
                    (__attribute__((address_space(3))) void*)&lds[3 * 4096 + (lb >> 1)], 16, 0, 0);
            }
        }
        __syncthreads();

        bf16x8 ah[4], bh[4], al[4], bl[4];
#pragma unroll
        for (int m = 0; m < 4; ++m) {
            const int r  = wm + m * 16 + fr;
            const int cb = fcb ^ ((r & 6) << 3);
            ah[m] = *(const bf16x8*)&lds[0 * 4096 + r * 32 + (cb >> 1)];
            if (SPLIT == 3) al[m] = *(const bf16x8*)&lds[2 * 4096 + r * 32 + (cb >> 1)];
        }
#pragma unroll
        for (int n = 0; n < 4; ++n) {
            const int r  = wn + n * 16 + fr;
            const int cb = fcb ^ ((r & 6) << 3);
            bh[n] = *(const bf16x8*)&lds[1 * 4096 + r * 32 + (cb >> 1)];
            if (SPLIT == 3) bl[n] = *(const bf16x8*)&lds[3 * 4096 + r * 32 + (cb >> 1)];
        }
#pragma unroll
        for (int m = 0; m < 4; ++m)
#pragma unroll
            for (int n = 0; n < 4; ++n) {
                acc[m][n] = __builtin_amdgcn_mfma_f32_16x16x32_bf16(ah[m], bh[n], acc[m][n], 0, 0, 0);
                if (SPLIT == 3) {
                    acc[m][n] = __builtin_amdgcn_mfma_f32_16x16x32_bf16(ah[m], bl[n], acc[m][n], 0, 0, 0);
                    acc[m][n] = __builtin_amdgcn_mfma_f32_16x16x32_bf16(al[m], bh[n], acc[m][n], 0, 0, 0);
                }
            }
    }

    // epilogue: C/D layout col=lane&15, row=(lane>>4)*4+reg  [m89/m91]
#pragma unroll
    for (int n = 0; n < 4; ++n) {
        const int cg = col0 + wn + n * 16 + fr;
        const float bv = bias[cg];
#pragma unroll
        for (int m = 0; m < 4; ++m) {
#pragma unroll
            for (int j = 0; j < 4; ++j) {
                const int rg = row0 + wm + m * 16 + g * 4 + j;
                if (rg < M) {
                    const float v = acc[m][n][j] + bv;
                    if (OUTBF) ((ushort*)Cout)[(size_t)rg * N + cg] = f2b(v);
                    else       ((float*)Cout)[(size_t)rg * N + cg] = v;
                }
            }
        }
    }
}

// ===================== CSR build ============================================
__global__ void count_edges_k(const int* __restrict__ tgt, int* __restrict__ counts, int E)
{
    int e = blockIdx.x * blockDim.x + threadIdx.x;
    if (e < E) atomicAdd(&counts[tgt[e]], 1);
}

__global__ __launch_bounds__(1024) void scan_counts_k(
    const int* __restrict__ counts, int* __restrict__ indptr, int M)
{
    __shared__ int part[1024];
    const int t  = threadIdx.x;
    const int CH = (M + 1023) / 1024;
    const int base = t * CH;
    int sum = 0;
    for (int i = 0; i < CH; ++i) {
        int idx = base + i;
        if (idx < M) sum += counts[idx];
    }
    part[t] = sum;
    __syncthreads();
    for (int off = 1; off < 1024; off <<= 1) {
        int v = (t >= off) ? part[t - off] : 0;
        __syncthreads();
        part[t] += v;
        __syncthreads();
    }
    int excl = part[t] - sum;
    for (int i = 0; i < CH; ++i) {
        int idx = base + i;
        if (idx < M) { indptr[idx] = excl; excl += counts[idx]; }
    }
    if (t == 1023) indptr[M] = part[1023];
}

__global__ void scatter_edges_k(const int* __restrict__ src, const int* __restrict__ tgt,
                                const int* __restrict__ indptr, int* __restrict__ cursor,
                                int* __restrict__ slot_src, int E)
{
    int e = blockIdx.x * blockDim.x + threadIdx.x;
    if (e < E) {
        int t   = tgt[e];
        int pos = atomicAdd(&cursor[t], 1);
        slot_src[indptr[t] + pos] = src[e];
    }
}

// ===================== attention: one wave per node, full-row lanes =========
// qkv: M x 1536 bf16, cols [0,512)=q, [512,1024)=k, [1024,1536)=v, head-major.
// Lane l covers elements l*8..l*8+7 -> entirely inside head h = l>>3.
// Pass A: logits -> LDS (+ per-head max); Pass B: exp + PV accumulate.
__global__ __launch_bounds__(256) void attn2_k(
    const ushort* __restrict__ qkv, const int* __restrict__ indptr,
    const int* __restrict__ slot_src, ushort* __restrict__ obh, ushort* __restrict__ obl)
{
    __shared__ float albuf[4][CAP * 8];
    const int w = threadIdx.x >> 6;
    const int l = threadIdx.x & 63;
    const int node = blockIdx.x * 4 + w;
    const int h = l >> 3;
    const int beg = indptr[node], end = indptr[node + 1];
    const int d = end - beg;

    // q row in registers (fp32)
    float qf[8];
    {
        bf16x8 qv = *(const bf16x8*)(qkv + (size_t)node * 1536 + (l << 3));
#pragma unroll
        for (int j = 0; j < 8; ++j) qf[j] = b2f((ushort)qv[j]);
    }

    // ---- pass A: logits + per-head max ----
    float m = -INFINITY;
    for (int i = 0; i < d; ++i) {
        const int src = slot_src[beg + i];
        bf16x8 kv = *(const bf16x8*)(qkv + (size_t)src * 1536 + 512 + (l << 3));
        float p = 0.f;
#pragma unroll
        for (int j = 0; j < 8; ++j) p = fmaf(qf[j], b2f((ushort)kv[j]), p);
        p += __shfl_xor(p, 1);
        p += __shfl_xor(p, 2);
        p += __shfl_xor(p, 4);
        p *= 0.125f;                       // 1/sqrt(64); all 8 lanes of group hold p
        m = fmaxf(m, p);
        if (i < CAP && (l & 7) == 0) albuf[w][i * 8 + h] = p;
    }

    // ---- pass B: softmax + PV ----
    float acc[8] = {};
    float ssum = 0.f;
    for (int i = 0; i < d; ++i) {
        const int src = slot_src[beg + i];
        float p;
        if (i < CAP) {
            p = albuf[w][i * 8 + h];
        } else {   // recompute (astronomically rare; correctness fallback)
            bf16x8 kv = *(const bf16x8*)(qkv + (size_t)src * 1536 + 512 + (l << 3));
            float pp = 0.f;
#pragma unroll
            for (int j = 0; j < 8; ++j) pp = fmaf(qf[j], b2f((ushort)kv[j]), pp);
            pp += __shfl_xor(pp, 1);
            pp += __shfl_xor(pp, 2);
            pp += __shfl_xor(pp, 4);
            p = pp * 0.125f;
        }
        const float wgt = __expf(p - m);
        ssum += wgt;
        bf16x8 vv = *(const bf16x8*)(qkv + (size_t)src * 1536 + 1024 + (l << 3));
#pragma unroll
        for (int j = 0; j < 8; ++j) acc[j] = fmaf(wgt, b2f((ushort)vv[j]), acc[j]);
    }

    // ---- epilogue: normalize + split-bf16 store ----
    const float inv = (d > 0) ? 1.f / ssum : 0.f;
    ushort4 ph0, ph1, pl0, pl1;
    float o;
    o = acc[0] * inv; ph0.x = f2b(o); pl0.x = f2b(o - b2f(ph0.x));
    o = acc[1] * inv; ph0.y = f2b(o); pl0.y = f2b(o - b2f(ph0.y));
    o = acc[2] * inv; ph0.z = f2b(o); pl0.z = f2b(o - b2f(ph0.z));
    o = acc[3] * inv; ph0.w = f2b(o); pl0.w = f2b(o - b2f(ph0.w));
    o = acc[4] * inv; ph1.x = f2b(o); pl1.x = f2b(o - b2f(ph1.x));
    o = acc[5] * inv; ph1.y = f2b(o); pl1.y = f2b(o - b2f(ph1.y));
    o = acc[6] * inv; ph1.z = f2b(o); pl1.z = f2b(o - b2f(ph1.z));
    o = acc[7] * inv; ph1.w = f2b(o); pl1.w = f2b(o - b2f(ph1.w));
    const size_t ob_off = (size_t)node * 512 + (l << 3);
    *(ushort4*)(obh + ob_off)     = ph0;
    *(ushort4*)(obh + ob_off + 4) = ph1;
    *(ushort4*)(obl + ob_off)     = pl0;
    *(ushort4*)(obl + ob_off + 4) = pl1;
}

// ===================== launch ===============================================
extern "C" void kernel_launch(void* const* d_in, const int* in_sizes, int n_in,
                              void* d_out, int out_size, void* d_ws, size_t ws_size,
                              hipStream_t stream)
{
    const float* s   = (const float*)d_in[0];
    const int*   eix = (const int*)d_in[1];   // [2, E]: row0 = src, row1 = tgt
    const float* Wq  = (const float*)d_in[2];
    const float* bq  = (const float*)d_in[3];
    const float* Wkv = (const float*)d_in[4];
    const float* bkv = (const float*)d_in[5];
    const float* Wo  = (const float*)d_in[6];
    const float* bo  = (const float*)d_in[7];
    float* out = (float*)d_out;

    char* ws = (char*)d_ws;
    auto take = [&](size_t bytes) { char* p = ws; ws += (bytes + 255) & ~(size_t)255; return p; };
    ushort* qkv_b = (ushort*)take((size_t)MN * 1536 * 2);
    ushort* s_b   = (ushort*)take((size_t)MN * 512 * 2);
    ushort* obh   = (ushort*)take((size_t)MN * 512 * 2);
    ushort* obl   = (ushort*)take((size_t)MN * 512 * 2);
    ushort* Wc_b  = (ushort*)take((size_t)1536 * 512 * 2);
    ushort* Wo_h  = (ushort*)take((size_t)512 * 512 * 2);
    ushort* Wo_l  = (ushort*)take((size_t)512 * 512 * 2);
    float*  bc    = (float*)take(1536 * 4);
    int* counts   = (int*)take(MN * 4);
    int* cursor   = (int*)take(MN * 4);
    int* slot_src = (int*)take((size_t)NE * 4);
    int* indptr   = (int*)take((MN + 4) * 4);

    hipMemsetAsync(counts, 0, MN * 4, stream);
    hipMemsetAsync(cursor, 0, MN * 4, stream);

    // conversions / permutations
    conv_bf16_k<<<(MN * 512 / 4 + 255) / 256, 256, 0, stream>>>(s, s_b, MN * 512 / 4);
    conv_wc_k<<<(1536 * 512 / 4 + 255) / 256, 256, 0, stream>>>(Wq, Wkv, Wc_b);
    bias_perm_k<<<6, 256, 0, stream>>>(bq, bkv, bc);
    conv_split_k<<<(512 * 512 / 4 + 255) / 256, 256, 0, stream>>>(Wo, Wo_h, Wo_l, 512 * 512 / 4);

    // CSR by target
    count_edges_k<<<NE / 256, 256, 0, stream>>>(eix + NE, counts, NE);
    scan_counts_k<<<1, 1024, 0, stream>>>(counts, indptr, MN);
    scatter_edges_k<<<NE / 256, 256, 0, stream>>>(eix, eix + NE, indptr, cursor, slot_src, NE);

    // QKV projection: qkv_b = s_b @ Wc_b^T + bc  (bf16 out, cols q|k|v)
    dim3 g1((MN + 127) / 128, 1536 / 128);
    gemm_mfma<1, true><<<g1, 256, 0, stream>>>(s_b, s_b, Wc_b, Wc_b, bc, qkv_b, MN, 1536, DM);

    // attention: one wave per node
    attn2_k<<<MN / 4, 256, 0, stream>>>(qkv_b, indptr, slot_src, obh, obl);

    // output projection (split-bf16, 3 MFMA): out = ob @ Wo^T + bo, fp32 out
    dim3 g2((MN + 127) / 128, 512 / 128);
    gemm_mfma<3, false><<<g2, 256, 0, stream>>>(obh, obl, Wo_h, Wo_l, bo, out, MN, 512, DM);
}

// Round 4
// 425.234 us; speedup vs baseline: 2.3440x; 1.0475x over previous
//
#include <hip/hip_runtime.h>
#include <cmath>

#define MN 20000
#define DM 512
#define NE 640000
#define CAP 128   // preloaded slot indices per node (deg>CAP falls back to global reads)

typedef short bf16x8 __attribute__((ext_vector_type(8)));
typedef float f32x4 __attribute__((ext_vector_type(4)));

// RNE fp32 -> bf16 (inputs finite)
__device__ __forceinline__ ushort f2b(float x) {
    unsigned u = __builtin_bit_cast(unsigned, x);
    u += 0x7FFF + ((u >> 16) & 1);
    return (ushort)(u >> 16);
}
__device__ __forceinline__ float b2f(ushort b) {
    return __builtin_bit_cast(float, (unsigned)b << 16);
}

// ===================== conversion kernels ===================================
__global__ void conv_bf16_k(const float* __restrict__ in, ushort* __restrict__ out, int n4) {
    int i = blockIdx.x * blockDim.x + threadIdx.x;
    if (i >= n4) return;
    float4 v = ((const float4*)in)[i];
    ushort4 o = { f2b(v.x), f2b(v.y), f2b(v.z), f2b(v.w) };
    ((ushort4*)out)[i] = o;
}

// combined weight rows reordered so qkv output cols = [q(512) | k 8x64 | v 8x64]
__device__ __forceinline__ const float* wc_src_row(int r, const float* Wq, const float* Wkv) {
    if (r < 512) return Wq + ((size_t)r << 9);
    if (r < 1024) { int h = (r - 512) >> 6, j = (r - 512) & 63;  return Wkv + ((size_t)(h * 128 + j) << 9); }
    { int h = (r - 1024) >> 6, j = (r - 1024) & 63; return Wkv + ((size_t)(h * 128 + 64 + j) << 9); }
}

__global__ void conv_wc_k(const float* __restrict__ Wq, const float* __restrict__ Wkv,
                          ushort* __restrict__ out) {
    int i = blockIdx.x * blockDim.x + threadIdx.x;
    if (i >= 1536 * 512 / 4) return;
    int e = i * 4;
    int row = e >> 9, col = e & 511;
    float4 v = *(const float4*)(wc_src_row(row, Wq, Wkv) + col);
    ushort4 o = { f2b(v.x), f2b(v.y), f2b(v.z), f2b(v.w) };
    ((ushort4*)out)[i] = o;
}

__global__ void bias_perm_k(const float* __restrict__ bq, const float* __restrict__ bkv,
                            float* __restrict__ bc) {
    int r = blockIdx.x * blockDim.x + threadIdx.x;
    if (r >= 1536) return;
    float v;
    if (r < 512) v = bq[r];
    else if (r < 1024) { int h = (r - 512) >> 6, j = (r - 512) & 63;  v = bkv[h * 128 + j]; }
    else               { int h = (r - 1024) >> 6, j = (r - 1024) & 63; v = bkv[h * 128 + 64 + j]; }
    bc[r] = v;
}

// fp32 -> (bf16 hi, bf16 lo) split
__global__ void conv_split_k(const float* __restrict__ in, ushort* __restrict__ oh,
                             ushort* __restrict__ ol, int n4) {
    int i = blockIdx.x * blockDim.x + threadIdx.x;
    if (i >= n4) return;
    float4 v = ((const float4*)in)[i];
    ushort4 h, l;
    h.x = f2b(v.x); l.x = f2b(v.x - b2f(h.x));
    h.y = f2b(v.y); l.y = f2b(v.y - b2f(h.y));
    h.z = f2b(v.z); l.z = f2b(v.z - b2f(h.z));
    h.w = f2b(v.w); l.w = f2b(v.w - b2f(h.w));
    ((ushort4*)oh)[i] = h;
    ((ushort4*)ol)[i] = l;
}

// ===================== MFMA GEMM: C = A @ B^T + bias ========================
// 128x128 tile, BK=32, 256 threads (4 waves, 2x2 of 64x64). LDS XOR-swizzled
// via pre-swizzled global source (global_load_lds writes linearly).
template<int SPLIT, bool OUTBF>
__global__ __launch_bounds__(256) void gemm_mfma(
    const ushort* __restrict__ Ah, const ushort* __restrict__ Al,
    const ushort* __restrict__ Bh, const ushort* __restrict__ Bl,
    const float* __restrict__ bias, void* __restrict__ Cout, int M, int N, int K)
{
    __shared__ ushort lds[4 * 4096];   // 0=A_hi 1=B_hi 2=A_lo 3=B_lo (8KB each)
    const int tid = threadIdx.x;
    const int row0 = blockIdx.x * 128, col0 = blockIdx.y * 128;
    const int wid = tid >> 6, l = tid & 63;
    const int wm = (wid >> 1) * 64, wn = (wid & 1) * 64;
    const int fr = l & 15, g = l >> 4;
    const int fcb = g << 4;

    f32x4 acc[4][4] = {};

    for (int k0 = 0; k0 < K; k0 += 32) {
        __syncthreads();
#pragma unroll
        for (int c = 0; c < 2; ++c) {
            const int lb  = c * 4096 + tid * 16;
            const int r   = lb >> 6;
            const int cbs = (lb & 63) ^ ((r & 6) << 3);
            const int ar  = min(row0 + r, M - 1);
            const int br  = col0 + r;
            const size_t aoff = (size_t)ar * K + k0 + (cbs >> 1);
            const size_t boff = (size_t)br * K + k0 + (cbs >> 1);
            __builtin_amdgcn_global_load_lds(
                (const __attribute__((address_space(1))) void*)(Ah + aoff),
                (__attribute__((address_space(3))) void*)&lds[0 * 4096 + (lb >> 1)], 16, 0, 0);
            __builtin_amdgcn_global_load_lds(
                (const __attribute__((address_space(1))) void*)(Bh + boff),
                (__attribute__((address_space(3))) void*)&lds[1 * 4096 + (lb >> 1)], 16, 0, 0);
            if (SPLIT == 3) {
                __builtin_amdgcn_global_load_lds(
                    (const __attribute__((address_space(1))) void*)(Al + aoff),
                    (__attribute__((address_space(3))) void*)&lds[2 * 4096 + (lb >> 1)], 16, 0, 0);
                __builtin_amdgcn_global_load_lds(
                    (const __attribute__((address_space(1))) void*)(Bl + boff),
                    (__attribute__((address_space(3))) void*)&lds[3 * 4096 + (lb >> 1)], 16, 0, 0);
            }
        }
        __syncthreads();

        bf16x8 ah[4], bh[4], al[4], bl[4];
#pragma unroll
        for (int m = 0; m < 4; ++m) {
            const int r  = wm + m * 16 + fr;
            const int cb = fcb ^ ((r & 6) << 3);
            ah[m] = *(const bf16x8*)&lds[0 * 4096 + r * 32 + (cb >> 1)];
            if (SPLIT == 3) al[m] = *(const bf16x8*)&lds[2 * 4096 + r * 32 + (cb >> 1)];
        }
#pragma unroll
        for (int n = 0; n < 4; ++n) {
            const int r  = wn + n * 16 + fr;
            const int cb = fcb ^ ((r & 6) << 3);
            bh[n] = *(const bf16x8*)&lds[1 * 4096 + r * 32 + (cb >> 1)];
            if (SPLIT == 3) bl[n] = *(const bf16x8*)&lds[3 * 4096 + r * 32 + (cb >> 1)];
        }
#pragma unroll
        for (int m = 0; m < 4; ++m)
#pragma unroll
            for (int n = 0; n < 4; ++n) {
                acc[m][n] = __builtin_amdgcn_mfma_f32_16x16x32_bf16(ah[m], bh[n], acc[m][n], 0, 0, 0);
                if (SPLIT == 3) {
                    acc[m][n] = __builtin_amdgcn_mfma_f32_16x16x32_bf16(ah[m], bl[n], acc[m][n], 0, 0, 0);
                    acc[m][n] = __builtin_amdgcn_mfma_f32_16x16x32_bf16(al[m], bh[n], acc[m][n], 0, 0, 0);
                }
            }
    }

    // epilogue: C/D layout col=lane&15, row=(lane>>4)*4+reg  [m89/m91]
#pragma unroll
    for (int n = 0; n < 4; ++n) {
        const int cg = col0 + wn + n * 16 + fr;
        const float bv = bias[cg];
#pragma unroll
        for (int m = 0; m < 4; ++m) {
#pragma unroll
            for (int j = 0; j < 4; ++j) {
                const int rg = row0 + wm + m * 16 + g * 4 + j;
                if (rg < M) {
                    const float v = acc[m][n][j] + bv;
                    if (OUTBF) ((ushort*)Cout)[(size_t)rg * N + cg] = f2b(v);
                    else       ((float*)Cout)[(size_t)rg * N + cg] = v;
                }
            }
        }
    }
}

// ===================== CSR build ============================================
__global__ void count_edges_k(const int* __restrict__ tgt, int* __restrict__ counts, int E)
{
    int e = blockIdx.x * blockDim.x + threadIdx.x;
    if (e < E) atomicAdd(&counts[tgt[e]], 1);
}

__global__ __launch_bounds__(1024) void scan_counts_k(
    const int* __restrict__ counts, int* __restrict__ indptr, int M)
{
    __shared__ int part[1024];
    const int t  = threadIdx.x;
    const int CH = (M + 1023) / 1024;
    const int base = t * CH;
    int sum = 0;
    for (int i = 0; i < CH; ++i) {
        int idx = base + i;
        if (idx < M) sum += counts[idx];
    }
    part[t] = sum;
    __syncthreads();
    for (int off = 1; off < 1024; off <<= 1) {
        int v = (t >= off) ? part[t - off] : 0;
        __syncthreads();
        part[t] += v;
        __syncthreads();
    }
    int excl = part[t] - sum;
    for (int i = 0; i < CH; ++i) {
        int idx = base + i;
        if (idx < M) { indptr[idx] = excl; excl += counts[idx]; }
    }
    if (t == 1023) indptr[M] = part[1023];
}

__global__ void scatter_edges_k(const int* __restrict__ src, const int* __restrict__ tgt,
                                const int* __restrict__ indptr, int* __restrict__ cursor,
                                int* __restrict__ slot_src, int E)
{
    int e = blockIdx.x * blockDim.x + threadIdx.x;
    if (e < E) {
        int t   = tgt[e];
        int pos = atomicAdd(&cursor[t], 1);
        slot_src[indptr[t] + pos] = src[e];
    }
}

// ===================== attention: single pass, no max subtraction ===========
// Softmax is shift-invariant; logits ~N(0,1), |p|max ~6 << 87 -> exp(p) safe.
// qkv: M x 1536 bf16 [q(512)|k(512)|v(512)], head-major. One wave per node;
// lane l covers elements l*8..l*8+7 of every row (head h = l>>3).
// Slot list preloaded to LDS; 4-edge unroll puts 8 gathers in flight.
__global__ __launch_bounds__(256) void attn3_k(
    const ushort* __restrict__ qkv, const int* __restrict__ indptr,
    const int* __restrict__ slot_src, ushort* __restrict__ obh, ushort* __restrict__ obl)
{
    __shared__ int slots[4][CAP];
    const int w = threadIdx.x >> 6;
    const int l = threadIdx.x & 63;
    const int node = blockIdx.x * 4 + w;
    const int beg = indptr[node], end = indptr[node + 1];
    const int d = end - beg;

    for (int i = l; i < d && i < CAP; i += 64) slots[w][i] = slot_src[beg + i];
    __syncthreads();

    float qf[8];
    {
        bf16x8 qv = *(const bf16x8*)(qkv + (size_t)node * 1536 + (l << 3));
#pragma unroll
        for (int j = 0; j < 8; ++j) qf[j] = b2f((ushort)qv[j]);
    }

    float acc[8] = {};
    float ssum = 0.f;

    int i = 0;
    for (; i + 4 <= d; i += 4) {
        const int s0 = (i + 0 < CAP) ? slots[w][i + 0] : slot_src[beg + i + 0];
        const int s1 = (i + 1 < CAP) ? slots[w][i + 1] : slot_src[beg + i + 1];
        const int s2 = (i + 2 < CAP) ? slots[w][i + 2] : slot_src[beg + i + 2];
        const int s3 = (i + 3 < CAP) ? slots[w][i + 3] : slot_src[beg + i + 3];
        const ushort* r0 = qkv + (size_t)s0 * 1536 + (l << 3);
        const ushort* r1 = qkv + (size_t)s1 * 1536 + (l << 3);
        const ushort* r2 = qkv + (size_t)s2 * 1536 + (l << 3);
        const ushort* r3 = qkv + (size_t)s3 * 1536 + (l << 3);
        bf16x8 k0 = *(const bf16x8*)(r0 + 512);
        bf16x8 v0 = *(const bf16x8*)(r0 + 1024);
        bf16x8 k1 = *(const bf16x8*)(r1 + 512);
        bf16x8 v1 = *(const bf16x8*)(r1 + 1024);
        bf16x8 k2 = *(const bf16x8*)(r2 + 512);
        bf16x8 v2 = *(const bf16x8*)(r2 + 1024);
        bf16x8 k3 = *(const bf16x8*)(r3 + 512);
        bf16x8 v3 = *(const bf16x8*)(r3 + 1024);

        float p0 = 0.f, p1 = 0.f, p2 = 0.f, p3 = 0.f;
#pragma unroll
        for (int j = 0; j < 8; ++j) {
            p0 = fmaf(qf[j], b2f((ushort)k0[j]), p0);
            p1 = fmaf(qf[j], b2f((ushort)k1[j]), p1);
            p2 = fmaf(qf[j], b2f((ushort)k2[j]), p2);
            p3 = fmaf(qf[j], b2f((ushort)k3[j]), p3);
        }
        p0 += __shfl_xor(p0, 1); p0 += __shfl_xor(p0, 2); p0 += __shfl_xor(p0, 4);
        p1 += __shfl_xor(p1, 1); p1 += __shfl_xor(p1, 2); p1 += __shfl_xor(p1, 4);
        p2 += __shfl_xor(p2, 1); p2 += __shfl_xor(p2, 2); p2 += __shfl_xor(p2, 4);
        p3 += __shfl_xor(p3, 1); p3 += __shfl_xor(p3, 2); p3 += __shfl_xor(p3, 4);

        const float w0 = __expf(p0 * 0.125f);
        const float w1 = __expf(p1 * 0.125f);
        const float w2 = __expf(p2 * 0.125f);
        const float w3 = __expf(p3 * 0.125f);
        ssum += (w0 + w1) + (w2 + w3);
#pragma unroll
        for (int j = 0; j < 8; ++j) {
            float a = acc[j];
            a = fmaf(w0, b2f((ushort)v0[j]), a);
            a = fmaf(w1, b2f((ushort)v1[j]), a);
            a = fmaf(w2, b2f((ushort)v2[j]), a);
            a = fmaf(w3, b2f((ushort)v3[j]), a);
            acc[j] = a;
        }
    }
    for (; i < d; ++i) {
        const int s0 = (i < CAP) ? slots[w][i] : slot_src[beg + i];
        const ushort* r0 = qkv + (size_t)s0 * 1536 + (l << 3);
        bf16x8 k0 = *(const bf16x8*)(r0 + 512);
        bf16x8 v0 = *(const bf16x8*)(r0 + 1024);
        float p0 = 0.f;
#pragma unroll
        for (int j = 0; j < 8; ++j) p0 = fmaf(qf[j], b2f((ushort)k0[j]), p0);
        p0 += __shfl_xor(p0, 1); p0 += __shfl_xor(p0, 2); p0 += __shfl_xor(p0, 4);
        const float w0 = __expf(p0 * 0.125f);
        ssum += w0;
#pragma unroll
        for (int j = 0; j < 8; ++j) acc[j] = fmaf(w0, b2f((ushort)v0[j]), acc[j]);
    }

    // epilogue: normalize + split-bf16 store
    const float inv = (d > 0) ? 1.f / ssum : 0.f;
    ushort4 ph0, ph1, pl0, pl1;
    float o;
    o = acc[0] * inv; ph0.x = f2b(o); pl0.x = f2b(o - b2f(ph0.x));
    o = acc[1] * inv; ph0.y = f2b(o); pl0.y = f2b(o - b2f(ph0.y));
    o = acc[2] * inv; ph0.z = f2b(o); pl0.z = f2b(o - b2f(ph0.z));
    o = acc[3] * inv; ph0.w = f2b(o); pl0.w = f2b(o - b2f(ph0.w));
    o = acc[4] * inv; ph1.x = f2b(o); pl1.x = f2b(o - b2f(ph1.x));
    o = acc[5] * inv; ph1.y = f2b(o); pl1.y = f2b(o - b2f(ph1.y));
    o = acc[6] * inv; ph1.z = f2b(o); pl1.z = f2b(o - b2f(ph1.z));
    o = acc[7] * inv; ph1.w = f2b(o); pl1.w = f2b(o - b2f(ph1.w));
    const size_t ob_off = (size_t)node * 512 + (l << 3);
    *(ushort4*)(obh + ob_off)     = ph0;
    *(ushort4*)(obh + ob_off + 4) = ph1;
    *(ushort4*)(obl + ob_off)     = pl0;
    *(ushort4*)(obl + ob_off + 4) = pl1;
}

// ===================== launch ===============================================
extern "C" void kernel_launch(void* const* d_in, const int* in_sizes, int n_in,
                              void* d_out, int out_size, void* d_ws, size_t ws_size,
                              hipStream_t stream)
{
    const float* s   = (const float*)d_in[0];
    const int*   eix = (const int*)d_in[1];   // [2, E]: row0 = src, row1 = tgt
    const float* Wq  = (const float*)d_in[2];
    const float* bq  = (const float*)d_in[3];
    const float* Wkv = (const float*)d_in[4];
    const float* bkv = (const float*)d_in[5];
    const float* Wo  = (const float*)d_in[6];
    const float* bo  = (const float*)d_in[7];
    float* out = (float*)d_out;

    char* ws = (char*)d_ws;
    auto take = [&](size_t bytes) { char* p = ws; ws += (bytes + 255) & ~(size_t)255; return p; };
    ushort* qkv_b = (ushort*)take((size_t)MN * 1536 * 2);
    ushort* s_b   = (ushort*)take((size_t)MN * 512 * 2);
    ushort* obh   = (ushort*)take((size_t)MN * 512 * 2);
    ushort* obl   = (ushort*)take((size_t)MN * 512 * 2);
    ushort* Wc_b  = (ushort*)take((size_t)1536 * 512 * 2);
    ushort* Wo_h  = (ushort*)take((size_t)512 * 512 * 2);
    ushort* Wo_l  = (ushort*)take((size_t)512 * 512 * 2);
    float*  bc    = (float*)take(1536 * 4);
    int* counts   = (int*)take(MN * 4);
    int* cursor   = (int*)take(MN * 4);
    int* slot_src = (int*)take((size_t)NE * 4);
    int* indptr   = (int*)take((MN + 4) * 4);

    hipMemsetAsync(counts, 0, MN * 4, stream);
    hipMemsetAsync(cursor, 0, MN * 4, stream);

    // conversions / permutations
    conv_bf16_k<<<(MN * 512 / 4 + 255) / 256, 256, 0, stream>>>(s, s_b, MN * 512 / 4);
    conv_wc_k<<<(1536 * 512 / 4 + 255) / 256, 256, 0, stream>>>(Wq, Wkv, Wc_b);
    bias_perm_k<<<6, 256, 0, stream>>>(bq, bkv, bc);
    conv_split_k<<<(512 * 512 / 4 + 255) / 256, 256, 0, stream>>>(Wo, Wo_h, Wo_l, 512 * 512 / 4);

    // CSR by target
    count_edges_k<<<NE / 256, 256, 0, stream>>>(eix + NE, counts, NE);
    scan_counts_k<<<1, 1024, 0, stream>>>(counts, indptr, MN);
    scatter_edges_k<<<NE / 256, 256, 0, stream>>>(eix, eix + NE, indptr, cursor, slot_src, NE);

    // QKV projection: qkv_b = s_b @ Wc_b^T + bc  (bf16 out, cols q|k|v)
    dim3 g1((MN + 127) / 128, 1536 / 128);
    gemm_mfma<1, true><<<g1, 256, 0, stream>>>(s_b, s_b, Wc_b, Wc_b, bc, qkv_b, MN, 1536, DM);

    // attention: one wave per node, single pass
    attn3_k<<<MN / 4, 256, 0, stream>>>(qkv_b, indptr, slot_src, obh, obl);

    // output projection (split-bf16, 3 MFMA): out = ob @ Wo^T + bo, fp32 out
    dim3 g2((MN + 127) / 128, 512 / 128);
    gemm_mfma<3, false><<<g2, 256, 0, stream>>>(obh, obl, Wo_h, Wo_l, bo, out, MN, 512, DM);
}